// Round 1
// baseline (248.104 us; speedup 1.0000x reference)
//
#include <hip/hip_runtime.h>
#include <hip/hip_bf16.h>
#include <stdint.h>

#define C_DIM 128
#define H_DIM 5

// ---------------- K0: Wa[k][j] = sum_c W[k, (j%5)*128+c] * att[j%5][c] ----------------
__global__ void wa_kernel(const float* __restrict__ W, const float* __restrict__ att_src,
                          const float* __restrict__ att_dst, float* __restrict__ Wa) {
    int t = blockIdx.x * blockDim.x + threadIdx.x;
    if (t >= C_DIM * 10) return;
    int k = t / 10, j = t % 10;
    int h = j % 5;
    const float* att = ((j < 5) ? att_src : att_dst) + h * C_DIM;
    const float* w = W + (size_t)k * (H_DIM * C_DIM) + h * C_DIM;
    float sum = 0.f;
#pragma unroll 8
    for (int c = 0; c < C_DIM; ++c) sum = fmaf(w[c], att[c], sum);
    Wa[k * 10 + j] = sum;
}

// ---------------- K1: alpha_{src,dst}[n][h] = sum_k F[n,k] * Wa[k][j] ----------------
__global__ void alpha_kernel(const float* __restrict__ F, const float* __restrict__ Wa,
                             float* __restrict__ asrc, float* __restrict__ adst, int N) {
    int t = blockIdx.x * blockDim.x + threadIdx.x;
    if (t >= N * 10) return;
    int n = t / 10, j = t % 10;
    const float* f = F + (size_t)n * C_DIM;
    float sum = 0.f;
#pragma unroll 8
    for (int k = 0; k < C_DIM; ++k) sum = fmaf(f[k], Wa[k * 10 + j], sum);
    if (j < 5) asrc[n * 5 + j] = sum;
    else       adst[n * 5 + (j - 5)] = sum;
}

// ---------------- K2: h = F @ W  (fp32 compute, bf16 store), tiled 64x64x32 ----------------
__global__ __launch_bounds__(256) void gemm_h_kernel(const float* __restrict__ A,
                                                     const float* __restrict__ B,
                                                     __hip_bfloat16* __restrict__ Hout, int M) {
    __shared__ float As[64][33];
    __shared__ float Bs[32][65];
    int by = blockIdx.x;          // row block
    int bx = blockIdx.y;          // col block (0..9)
    int tid = threadIdx.x;
    int tx = tid % 16, ty = tid / 16;
    int row0 = by * 64, col0 = bx * 64;
    float acc[4][4] = {};
    for (int kb = 0; kb < 128; kb += 32) {
#pragma unroll
        for (int t = 0; t < 8; ++t) {
            int l = tid + t * 256;
            int r = l >> 5, c = l & 31;
            int grow = row0 + r;
            As[r][c] = (grow < M) ? A[(size_t)grow * 128 + kb + c] : 0.f;
        }
#pragma unroll
        for (int t = 0; t < 8; ++t) {
            int l = tid + t * 256;
            int r = l >> 6, c = l & 63;
            Bs[r][c] = B[(size_t)(kb + r) * 640 + col0 + c];
        }
        __syncthreads();
#pragma unroll
        for (int k = 0; k < 32; ++k) {
            float a[4], b[4];
#pragma unroll
            for (int i = 0; i < 4; ++i) a[i] = As[ty * 4 + i][k];
#pragma unroll
            for (int j = 0; j < 4; ++j) b[j] = Bs[k][tx * 4 + j];
#pragma unroll
            for (int i = 0; i < 4; ++i)
#pragma unroll
                for (int j = 0; j < 4; ++j) acc[i][j] = fmaf(a[i], b[j], acc[i][j]);
        }
        __syncthreads();
    }
#pragma unroll
    for (int i = 0; i < 4; ++i) {
        int r = row0 + ty * 4 + i;
        if (r < M) {
            ushort4 pk;
            __hip_bfloat16 b0 = __float2bfloat16(acc[i][0]);
            __hip_bfloat16 b1 = __float2bfloat16(acc[i][1]);
            __hip_bfloat16 b2 = __float2bfloat16(acc[i][2]);
            __hip_bfloat16 b3 = __float2bfloat16(acc[i][3]);
            pk.x = *reinterpret_cast<unsigned short*>(&b0);
            pk.y = *reinterpret_cast<unsigned short*>(&b1);
            pk.z = *reinterpret_cast<unsigned short*>(&b2);
            pk.w = *reinterpret_cast<unsigned short*>(&b3);
            *reinterpret_cast<ushort4*>(&Hout[(size_t)r * 640 + col0 + tx * 4]) = pk;
        }
    }
}

// ---------------- K3: degree count (random edges + self loops) ----------------
__global__ void count_kernel(const int* __restrict__ dstArr, int* __restrict__ deg, int E, int N) {
    int e = blockIdx.x * blockDim.x + threadIdx.x;
    if (e >= E + N) return;
    int i = (e < E) ? dstArr[e] : (e - E);
    atomicAdd(&deg[i], 1);
}

// ---------------- K4: single-block exclusive scan over deg -> rowptr ----------------
__global__ __launch_bounds__(1024) void scan_kernel(const int* __restrict__ deg,
                                                    int* __restrict__ rowptr, int n) {
    __shared__ int lds[1024];
    int t = threadIdx.x;
    const int CH = (n + 1023) / 1024;
    int begin = t * CH;
    int end = begin + CH; if (end > n) end = n;
    int sum = 0;
    for (int i = begin; i < end && i < n; ++i) sum += deg[i];
    lds[t] = sum;
    __syncthreads();
    for (int off = 1; off < 1024; off <<= 1) {
        int v = 0;
        if (t >= off) v = lds[t - off];
        __syncthreads();
        if (t >= off) lds[t] += v;
        __syncthreads();
    }
    int base = (t == 0) ? 0 : lds[t - 1];
    for (int i = begin; i < end && i < n; ++i) {
        rowptr[i] = base;
        base += deg[i];
    }
    if (t == 1023) rowptr[n] = lds[1023];
}

// ---------------- K5: scatter src indices into CSR ----------------
__global__ void scatter_kernel(const int* __restrict__ srcArr, const int* __restrict__ dstArr,
                               const int* __restrict__ rowptr, int* __restrict__ cnt,
                               int* __restrict__ col, int E, int N) {
    int e = blockIdx.x * blockDim.x + threadIdx.x;
    if (e >= E + N) return;
    int i, s;
    if (e < E) { i = dstArr[e]; s = srcArr[e]; }
    else       { i = e - E;    s = i; }
    int pos = rowptr[i] + atomicAdd(&cnt[i], 1);
    col[pos] = s;
}

// ---------------- K6: per-node fused softmax + aggregation + epilogue ----------------
__global__ __launch_bounds__(64) void gat_aggregate(
    const int* __restrict__ rowptr, const int* __restrict__ col,
    const float* __restrict__ asrc, const float* __restrict__ adst,
    const __hip_bfloat16* __restrict__ hbf,
    const float* __restrict__ features, const float* __restrict__ bias,
    float* __restrict__ out, int N) {
    int i = blockIdx.x;
    int lane = threadIdx.x;
    float ad[5];
#pragma unroll
    for (int h = 0; h < 5; ++h) ad[h] = adst[i * 5 + h];
    float s[5] = {0.f, 0.f, 0.f, 0.f, 0.f};
    float acc0[5] = {0.f, 0.f, 0.f, 0.f, 0.f};
    float acc1[5] = {0.f, 0.f, 0.f, 0.f, 0.f};
    int p0 = rowptr[i], p1 = rowptr[i + 1];
    const uint32_t* hbase = (const uint32_t*)hbf;  // 2 bf16 per u32
    for (int p = p0; p < p1; ++p) {
        int j = col[p];
        float w[5];
#pragma unroll
        for (int h = 0; h < 5; ++h) {
            float e = asrc[j * 5 + h] + ad[h];
            e = (e > 0.f) ? e : 0.2f * e;
            w[h] = __expf(e);
            s[h] += w[h];
        }
        size_t base = (size_t)j * 320 + lane;  // u32 units: row stride 640 bf16 = 320 u32
#pragma unroll
        for (int h = 0; h < 5; ++h) {
            uint32_t u = hbase[base + h * 64];
            float x0 = __uint_as_float(u << 16);
            float x1 = __uint_as_float(u & 0xffff0000u);
            acc0[h] = fmaf(w[h], x0, acc0[h]);
            acc1[h] = fmaf(w[h], x1, acc1[h]);
        }
    }
    float o0 = 0.f, o1 = 0.f;
#pragma unroll
    for (int h = 0; h < 5; ++h) {
        float inv = 1.f / (s[h] + 1e-16f);
        o0 = fmaf(acc0[h], inv, o0);
        o1 = fmaf(acc1[h], inv, o1);
    }
    o0 *= 0.2f;  // mean over 5 heads
    o1 *= 0.2f;
    int c = 2 * lane;
    size_t oidx = (size_t)i * C_DIM + c;
    float2 f = *reinterpret_cast<const float2*>(features + oidx);
    float2 r;
    r.x = f.x + bias[c] + o0;
    r.y = f.y + bias[c + 1] + o1;
    *reinterpret_cast<float2*>(out + oidx) = r;
}

// ---------------- launch ----------------
static inline char* bump(char*& p, size_t bytes) {
    char* r = p;
    p += (bytes + 255) & ~(size_t)255;
    return r;
}

extern "C" void kernel_launch(void* const* d_in, const int* in_sizes, int n_in,
                              void* d_out, int out_size, void* d_ws, size_t ws_size,
                              hipStream_t stream) {
    const float* features = (const float*)d_in[0];
    const float* W        = (const float*)d_in[1];
    const float* att_src  = (const float*)d_in[2];
    const float* att_dst  = (const float*)d_in[3];
    const float* bias     = (const float*)d_in[4];
    const int*   edges    = (const int*)d_in[5];

    const int N = in_sizes[0] / C_DIM;
    const int E = in_sizes[5] / 2;
    const int EN = E + N;
    const int* srcArr = edges;
    const int* dstArr = edges + E;

    char* p = (char*)d_ws;
    float* Wa     = (float*)bump(p, C_DIM * 10 * sizeof(float));
    float* asrc   = (float*)bump(p, (size_t)N * 5 * sizeof(float));
    float* adst   = (float*)bump(p, (size_t)N * 5 * sizeof(float));
    __hip_bfloat16* hbf = (__hip_bfloat16*)bump(p, (size_t)N * 640 * sizeof(__hip_bfloat16));
    int* deg      = (int*)bump(p, (size_t)N * sizeof(int));
    int* cnt      = (int*)bump(p, (size_t)N * sizeof(int));
    int* rowptr   = (int*)bump(p, (size_t)(N + 1) * sizeof(int));
    int* col      = (int*)bump(p, (size_t)EN * sizeof(int));

    float* out = (float*)d_out;

    hipMemsetAsync(deg, 0, (size_t)N * sizeof(int), stream);
    hipMemsetAsync(cnt, 0, (size_t)N * sizeof(int), stream);

    // K0: Wa
    wa_kernel<<<(C_DIM * 10 + 255) / 256, 256, 0, stream>>>(W, att_src, att_dst, Wa);
    // K1: alphas
    alpha_kernel<<<(N * 10 + 255) / 256, 256, 0, stream>>>(features, Wa, asrc, adst, N);
    // K2: h GEMM
    dim3 ggrid((N + 63) / 64, 10);
    gemm_h_kernel<<<ggrid, 256, 0, stream>>>(features, W, hbf, N);
    // K3: degrees
    count_kernel<<<(EN + 255) / 256, 256, 0, stream>>>(dstArr, deg, E, N);
    // K4: scan
    scan_kernel<<<1, 1024, 0, stream>>>(deg, rowptr, N);
    // K5: scatter
    scatter_kernel<<<(EN + 255) / 256, 256, 0, stream>>>(srcArr, dstArr, rowptr, cnt, col, E, N);
    // K6: aggregate + epilogue
    gat_aggregate<<<N, 64, 0, stream>>>(rowptr, col, asrc, adst, hbf, features, bias, out, N);
}

// Round 2
// 189.536 us; speedup vs baseline: 1.3090x; 1.3090x over previous
//
#include <hip/hip_runtime.h>
#include <hip/hip_bf16.h>
#include <stdint.h>

#define C_DIM 128
#define H_DIM 5

typedef __bf16 bf16x8 __attribute__((ext_vector_type(8)));
typedef float f32x4 __attribute__((ext_vector_type(4)));

static __device__ __forceinline__ ushort f2bf(float x) {
    __hip_bfloat16 b = __float2bfloat16(x);
    return *reinterpret_cast<ushort*>(&b);
}

// ---------------- K0: Wa[k][j] = sum_c W[k, (j%5)*128+c] * att[j%5][c] ----------------
__global__ void wa_kernel(const float* __restrict__ W, const float* __restrict__ att_src,
                          const float* __restrict__ att_dst, float* __restrict__ Wa) {
    int t = blockIdx.x * blockDim.x + threadIdx.x;
    if (t >= C_DIM * 10) return;
    int k = t / 10, j = t % 10;
    int h = j % 5;
    const float* att = ((j < 5) ? att_src : att_dst) + h * C_DIM;
    const float* w = W + (size_t)k * (H_DIM * C_DIM) + h * C_DIM;
    float sum = 0.f;
#pragma unroll 8
    for (int c = 0; c < C_DIM; ++c) sum = fmaf(w[c], att[c], sum);
    Wa[k * 10 + j] = sum;
}

// ---------------- K1: alpha_{src,dst}[n][h] = sum_k F[n,k] * Wa[k][j] (fp32 exact) ----------------
__global__ void alpha_kernel(const float* __restrict__ F, const float* __restrict__ Wa,
                             float* __restrict__ asrc, float* __restrict__ adst, int N) {
    int t = blockIdx.x * blockDim.x + threadIdx.x;
    if (t >= N * 10) return;
    int n = t / 10, j = t % 10;
    const float* f = F + (size_t)n * C_DIM;
    float sum = 0.f;
#pragma unroll 8
    for (int k = 0; k < C_DIM; ++k) sum = fmaf(f[k], Wa[k * 10 + j], sum);
    if (j < 5) asrc[n * 5 + j] = sum;
    else       adst[n * 5 + (j - 5)] = sum;
}

// ---------------- conv: features fp32 -> bf16 ----------------
__global__ void conv_A(const float* __restrict__ F, ushort* __restrict__ Abf, int total8) {
    int t = blockIdx.x * blockDim.x + threadIdx.x;
    if (t >= total8) return;
    const float4* f4 = reinterpret_cast<const float4*>(F) + (size_t)t * 2;
    float4 v0 = f4[0], v1 = f4[1];
    float vv[8] = {v0.x, v0.y, v0.z, v0.w, v1.x, v1.y, v1.z, v1.w};
    ushort u[8];
#pragma unroll
    for (int i = 0; i < 8; ++i) u[i] = f2bf(vv[i]);
    *reinterpret_cast<uint4*>(Abf + (size_t)t * 8) = *reinterpret_cast<uint4*>(u);
}

// ---------------- conv: W fp32 [128][640] -> Bt bf16 [640][128] ----------------
__global__ void conv_Bt(const float* __restrict__ W, ushort* __restrict__ Bt) {
    int t = blockIdx.x * blockDim.x + threadIdx.x;
    if (t >= 640 * 128) return;
    int c = t >> 7, k = t & 127;
    Bt[t] = f2bf(W[(size_t)k * 640 + c]);
}

// ---------------- K2: h = F @ W via bf16 MFMA, 128x64 tile, full K=128 in LDS ----------------
__global__ __launch_bounds__(256) void gemm_h_mfma(const ushort* __restrict__ Abf,
                                                   const ushort* __restrict__ Bt,
                                                   ushort* __restrict__ Hout, int M) {
    __shared__ ushort As[128][136];  // +8 pad -> 2-way bank conflicts only
    __shared__ ushort Bs[64][136];
    int tid = threadIdx.x;
    int row0 = blockIdx.x * 128;
    int col0 = blockIdx.y * 64;
    int seg = tid & 15, rb = tid >> 4;  // 16 segs of 16B per 256B row; 16 rows/pass
#pragma unroll
    for (int p = 0; p < 8; ++p) {
        int r = rb + p * 16;
        int gr = row0 + r;
        uint4 v = make_uint4(0u, 0u, 0u, 0u);
        if (gr < M) v = *reinterpret_cast<const uint4*>(Abf + (size_t)gr * 128 + seg * 8);
        *reinterpret_cast<uint4*>(&As[r][seg * 8]) = v;
    }
#pragma unroll
    for (int p = 0; p < 4; ++p) {
        int r = rb + p * 16;
        uint4 v = *reinterpret_cast<const uint4*>(Bt + (size_t)(col0 + r) * 128 + seg * 8);
        *reinterpret_cast<uint4*>(&Bs[r][seg * 8]) = v;
    }
    __syncthreads();

    int wave = tid >> 6, lane = tid & 63;
    int wr = (wave & 1) * 64;   // row half
    int wc = (wave >> 1) * 32;  // col half
    int lm = lane & 15, lk = (lane >> 4) * 8;
    f32x4 acc[4][2] = {};
#pragma unroll
    for (int kk = 0; kk < 4; ++kk) {
        int k = kk * 32 + lk;
        bf16x8 a[4], b[2];
#pragma unroll
        for (int m = 0; m < 4; ++m)
            a[m] = *reinterpret_cast<const bf16x8*>(&As[wr + m * 16 + lm][k]);
#pragma unroll
        for (int n = 0; n < 2; ++n)
            b[n] = *reinterpret_cast<const bf16x8*>(&Bs[wc + n * 16 + lm][k]);
#pragma unroll
        for (int m = 0; m < 4; ++m)
#pragma unroll
            for (int n = 0; n < 2; ++n)
                acc[m][n] = __builtin_amdgcn_mfma_f32_16x16x32_bf16(a[m], b[n], acc[m][n], 0, 0, 0);
    }
    // C/D layout: col = lane&15, row = (lane>>4)*4 + reg  [m89-verified]
    int r4 = (lane >> 4) * 4;
#pragma unroll
    for (int m = 0; m < 4; ++m) {
#pragma unroll
        for (int r = 0; r < 4; ++r) {
            int grow = row0 + wr + m * 16 + r4 + r;
            if (grow < M) {
#pragma unroll
                for (int n = 0; n < 2; ++n)
                    Hout[(size_t)grow * 640 + col0 + wc + n * 16 + lm] = f2bf(acc[m][n][r]);
            }
        }
    }
}

// ---------------- K3: degree count ----------------
__global__ void count_kernel(const int* __restrict__ dstArr, int* __restrict__ deg, int E, int N) {
    int e = blockIdx.x * blockDim.x + threadIdx.x;
    if (e >= E + N) return;
    int i = (e < E) ? dstArr[e] : (e - E);
    atomicAdd(&deg[i], 1);
}

// ---------------- K4: single-block scan -> rowptr ----------------
__global__ __launch_bounds__(1024) void scan_kernel(const int* __restrict__ deg,
                                                    int* __restrict__ rowptr, int n) {
    __shared__ int lds[1024];
    int t = threadIdx.x;
    const int CH = (n + 1023) / 1024;
    int begin = t * CH;
    int end = begin + CH; if (end > n) end = n;
    int sum = 0;
    for (int i = begin; i < end && i < n; ++i) sum += deg[i];
    lds[t] = sum;
    __syncthreads();
    for (int off = 1; off < 1024; off <<= 1) {
        int v = 0;
        if (t >= off) v = lds[t - off];
        __syncthreads();
        if (t >= off) lds[t] += v;
        __syncthreads();
    }
    int base = (t == 0) ? 0 : lds[t - 1];
    for (int i = begin; i < end && i < n; ++i) {
        rowptr[i] = base;
        base += deg[i];
    }
    if (t == 1023) rowptr[n] = lds[1023];
}

// ---------------- K5: scatter src indices into CSR ----------------
__global__ void scatter_kernel(const int* __restrict__ srcArr, const int* __restrict__ dstArr,
                               const int* __restrict__ rowptr, int* __restrict__ cnt,
                               int* __restrict__ col, int E, int N) {
    int e = blockIdx.x * blockDim.x + threadIdx.x;
    if (e >= E + N) return;
    int i, s;
    if (e < E) { i = dstArr[e]; s = srcArr[e]; }
    else       { i = e - E;    s = i; }
    int pos = rowptr[i] + atomicAdd(&cnt[i], 1);
    col[pos] = s;
}

// ---------------- K6: fused softmax + aggregation + epilogue; 1 wave/node, 4 nodes/block ----------------
// lane = 16*g + m : owns head g (g<4) channels m*8..m*8+7 ; head 4 replicated per group.
__global__ __launch_bounds__(256) void gat_aggregate(
    const int* __restrict__ rowptr, const int* __restrict__ col,
    const float* __restrict__ asrc, const float* __restrict__ adst,
    const ushort* __restrict__ hbf,
    const float* __restrict__ features, const float* __restrict__ bias,
    float* __restrict__ out, int N) {
    int node = blockIdx.x * 4 + (threadIdx.x >> 6);
    if (node >= N) return;  // no __syncthreads in this kernel -> safe
    int lane = threadIdx.x & 63;
    int g = lane >> 4, m = lane & 15;
    float adg = adst[node * 5 + g];
    float ad4 = adst[node * 5 + 4];
    int p0 = rowptr[node], p1 = rowptr[node + 1];
    float accG[8] = {}, acc4[8] = {};
    float sg = 0.f, s4 = 0.f;
    for (int p = p0; p < p1; ++p) {
        int j = col[p];
        float eg = asrc[j * 5 + g] + adg;
        float e4 = asrc[j * 5 + 4] + ad4;
        eg = (eg > 0.f) ? eg : 0.2f * eg;
        e4 = (e4 > 0.f) ? e4 : 0.2f * e4;
        float wg = __expf(eg), w4 = __expf(e4);
        sg += wg; s4 += w4;
        const uint4 q  = *reinterpret_cast<const uint4*>(hbf + (size_t)j * 640 + g * 128 + m * 8);
        const uint4 q4 = *reinterpret_cast<const uint4*>(hbf + (size_t)j * 640 + 512 + m * 8);
        uint32_t uu[4] = {q.x, q.y, q.z, q.w};
        uint32_t u4[4] = {q4.x, q4.y, q4.z, q4.w};
#pragma unroll
        for (int i = 0; i < 4; ++i) {
            float x0 = __uint_as_float(uu[i] << 16);
            float x1 = __uint_as_float(uu[i] & 0xffff0000u);
            accG[2 * i]     = fmaf(wg, x0, accG[2 * i]);
            accG[2 * i + 1] = fmaf(wg, x1, accG[2 * i + 1]);
            float y0 = __uint_as_float(u4[i] << 16);
            float y1 = __uint_as_float(u4[i] & 0xffff0000u);
            acc4[2 * i]     = fmaf(w4, y0, acc4[2 * i]);
            acc4[2 * i + 1] = fmaf(w4, y1, acc4[2 * i + 1]);
        }
    }
    float invg = 1.f / (sg + 1e-16f);
    float inv4 = 0.25f / (s4 + 1e-16f);  // 0.25: head-4 acc is replicated across the 4 groups
    float r[8];
#pragma unroll
    for (int e = 0; e < 8; ++e) r[e] = accG[e] * invg + acc4[e] * inv4;
#pragma unroll
    for (int e = 0; e < 8; ++e) r[e] += __shfl_xor(r[e], 16, 64);
#pragma unroll
    for (int e = 0; e < 8; ++e) r[e] += __shfl_xor(r[e], 32, 64);
    if (g == 0) {
        int c0 = m * 8;
        size_t base = (size_t)node * 128 + c0;
        float4 f0 = *reinterpret_cast<const float4*>(features + base);
        float4 f1 = *reinterpret_cast<const float4*>(features + base + 4);
        float4 b0 = *reinterpret_cast<const float4*>(bias + c0);
        float4 b1 = *reinterpret_cast<const float4*>(bias + c0 + 4);
        float4 o0, o1;
        o0.x = f0.x + b0.x + 0.2f * r[0];
        o0.y = f0.y + b0.y + 0.2f * r[1];
        o0.z = f0.z + b0.z + 0.2f * r[2];
        o0.w = f0.w + b0.w + 0.2f * r[3];
        o1.x = f1.x + b1.x + 0.2f * r[4];
        o1.y = f1.y + b1.y + 0.2f * r[5];
        o1.z = f1.z + b1.z + 0.2f * r[6];
        o1.w = f1.w + b1.w + 0.2f * r[7];
        *reinterpret_cast<float4*>(out + base) = o0;
        *reinterpret_cast<float4*>(out + base + 4) = o1;
    }
}

// ---------------- launch ----------------
static inline char* bump(char*& p, size_t bytes) {
    char* r = p;
    p += (bytes + 255) & ~(size_t)255;
    return r;
}

extern "C" void kernel_launch(void* const* d_in, const int* in_sizes, int n_in,
                              void* d_out, int out_size, void* d_ws, size_t ws_size,
                              hipStream_t stream) {
    const float* features = (const float*)d_in[0];
    const float* W        = (const float*)d_in[1];
    const float* att_src  = (const float*)d_in[2];
    const float* att_dst  = (const float*)d_in[3];
    const float* bias     = (const float*)d_in[4];
    const int*   edges    = (const int*)d_in[5];

    const int N = in_sizes[0] / C_DIM;
    const int E = in_sizes[5] / 2;
    const int EN = E + N;
    const int* srcArr = edges;
    const int* dstArr = edges + E;

    char* p = (char*)d_ws;
    float* Wa     = (float*)bump(p, C_DIM * 10 * sizeof(float));
    float* asrc   = (float*)bump(p, (size_t)N * 5 * sizeof(float));
    float* adst   = (float*)bump(p, (size_t)N * 5 * sizeof(float));
    ushort* hbf   = (ushort*)bump(p, (size_t)N * 640 * sizeof(ushort));
    ushort* Abf   = (ushort*)bump(p, (size_t)N * C_DIM * sizeof(ushort));
    ushort* Bt    = (ushort*)bump(p, 640 * 128 * sizeof(ushort));
    int* deg      = (int*)bump(p, (size_t)N * sizeof(int));
    int* cnt      = (int*)bump(p, (size_t)N * sizeof(int));
    int* rowptr   = (int*)bump(p, (size_t)(N + 1) * sizeof(int));
    int* col      = (int*)bump(p, (size_t)EN * sizeof(int));

    float* out = (float*)d_out;

    hipMemsetAsync(deg, 0, (size_t)N * sizeof(int), stream);
    hipMemsetAsync(cnt, 0, (size_t)N * sizeof(int), stream);

    wa_kernel<<<(C_DIM * 10 + 255) / 256, 256, 0, stream>>>(W, att_src, att_dst, Wa);
    alpha_kernel<<<(N * 10 + 255) / 256, 256, 0, stream>>>(features, Wa, asrc, adst, N);
    conv_A<<<((N * 16) + 255) / 256, 256, 0, stream>>>(features, Abf, N * 16);
    conv_Bt<<<(640 * 128 + 255) / 256, 256, 0, stream>>>(W, Bt);
    dim3 ggrid((N + 127) / 128, 10);
    gemm_h_mfma<<<ggrid, 256, 0, stream>>>(Abf, Bt, hbf, N);
    count_kernel<<<(EN + 255) / 256, 256, 0, stream>>>(dstArr, deg, E, N);
    scan_kernel<<<1, 1024, 0, stream>>>(deg, rowptr, N);
    scatter_kernel<<<(EN + 255) / 256, 256, 0, stream>>>(srcArr, dstArr, rowptr, cnt, col, E, N);
    gat_aggregate<<<(N + 3) / 4, 256, 0, stream>>>(rowptr, col, asrc, adst, hbf, features, bias, out, N);
}

// Round 3
// 162.489 us; speedup vs baseline: 1.5269x; 1.1665x over previous
//
#include <hip/hip_runtime.h>
#include <hip/hip_bf16.h>
#include <stdint.h>

#define C_DIM 128
#define H_DIM 5

typedef __bf16 bf16x8 __attribute__((ext_vector_type(8)));
typedef float f32x4 __attribute__((ext_vector_type(4)));

static __device__ __forceinline__ ushort f2bf(float x) {
    __hip_bfloat16 b = __float2bfloat16(x);
    return *reinterpret_cast<ushort*>(&b);
}

// ---------------- P0: fused independent prep: conv_A | conv_Bt | wa | count ----------------
__global__ __launch_bounds__(256) void prep0_kernel(
    const float* __restrict__ F, const float* __restrict__ W,
    const float* __restrict__ att_src, const float* __restrict__ att_dst,
    ushort* __restrict__ Abf, ushort* __restrict__ Bt, float* __restrict__ Wa,
    const int* __restrict__ dstArr, int* __restrict__ deg,
    int B1, int B2, int B3, int N, int E) {
    int b = blockIdx.x;
    int tid = threadIdx.x;
    if (b < B1) {
        // conv_A: features fp32 -> bf16, 8 elems/thread
        int t = b * 256 + tid;
        if (t < N * 16) {
            const float4* f4 = reinterpret_cast<const float4*>(F) + (size_t)t * 2;
            float4 v0 = f4[0], v1 = f4[1];
            float vv[8] = {v0.x, v0.y, v0.z, v0.w, v1.x, v1.y, v1.z, v1.w};
            ushort u[8];
#pragma unroll
            for (int i = 0; i < 8; ++i) u[i] = f2bf(vv[i]);
            *reinterpret_cast<uint4*>(Abf + (size_t)t * 8) = *reinterpret_cast<uint4*>(u);
        }
    } else if (b < B2) {
        // conv_Bt: W [128][640] -> Bt bf16 [640][128]
        int t = (b - B1) * 256 + tid;
        if (t < 640 * 128) {
            int c = t >> 7, k = t & 127;
            Bt[t] = f2bf(W[(size_t)k * 640 + c]);
        }
    } else if (b < B3) {
        // wa: Wa[k][j] = sum_c W[k, h*128+c]*att[h][c]
        int t = (b - B2) * 256 + tid;
        if (t < C_DIM * 10) {
            int k = t / 10, j = t % 10;
            int h = j % 5;
            const float* att = ((j < 5) ? att_src : att_dst) + h * C_DIM;
            const float* w = W + (size_t)k * (H_DIM * C_DIM) + h * C_DIM;
            float sum = 0.f;
#pragma unroll 8
            for (int c = 0; c < C_DIM; ++c) sum = fmaf(w[c], att[c], sum);
            Wa[k * 10 + j] = sum;
        }
    } else {
        // count degrees
        int e = (b - B3) * 256 + tid;
        if (e < E + N) {
            int i = (e < E) ? dstArr[e] : (e - E);
            atomicAdd(&deg[i], 1);
        }
    }
}

// ---------------- P1: fused alpha | scatter ----------------
__global__ __launch_bounds__(256) void prep1_kernel(
    const float* __restrict__ F, const float* __restrict__ Wa,
    float* __restrict__ asrc, float* __restrict__ adst,
    const int* __restrict__ srcArr, const int* __restrict__ dstArr,
    const int* __restrict__ rowptr, int* __restrict__ cnt, int* __restrict__ col,
    int B1, int N, int E) {
    int b = blockIdx.x;
    int tid = threadIdx.x;
    if (b < B1) {
        int t = b * 256 + tid;
        if (t < N * 10) {
            int n = t / 10, j = t % 10;
            const float* f = F + (size_t)n * C_DIM;
            float sum = 0.f;
#pragma unroll 8
            for (int k = 0; k < C_DIM; ++k) sum = fmaf(f[k], Wa[k * 10 + j], sum);
            if (j < 5) asrc[n * 5 + j] = sum;
            else       adst[n * 5 + (j - 5)] = sum;
        }
    } else {
        int e = (b - B1) * 256 + tid;
        if (e < E + N) {
            int i, s;
            if (e < E) { i = dstArr[e]; s = srcArr[e]; }
            else       { i = e - E;    s = i; }
            int pos = rowptr[i] + atomicAdd(&cnt[i], 1);
            col[pos] = s;
        }
    }
}

// ---------------- K2: h = F @ W via bf16 MFMA, 128x64 tile, full K=128 in LDS ----------------
__global__ __launch_bounds__(256) void gemm_h_mfma(const ushort* __restrict__ Abf,
                                                   const ushort* __restrict__ Bt,
                                                   ushort* __restrict__ Hout, int M) {
    __shared__ ushort As[128][136];
    __shared__ ushort Bs[64][136];
    int tid = threadIdx.x;
    int row0 = blockIdx.x * 128;
    int col0 = blockIdx.y * 64;
    int seg = tid & 15, rb = tid >> 4;
#pragma unroll
    for (int p = 0; p < 8; ++p) {
        int r = rb + p * 16;
        int gr = row0 + r;
        uint4 v = make_uint4(0u, 0u, 0u, 0u);
        if (gr < M) v = *reinterpret_cast<const uint4*>(Abf + (size_t)gr * 128 + seg * 8);
        *reinterpret_cast<uint4*>(&As[r][seg * 8]) = v;
    }
#pragma unroll
    for (int p = 0; p < 4; ++p) {
        int r = rb + p * 16;
        uint4 v = *reinterpret_cast<const uint4*>(Bt + (size_t)(col0 + r) * 128 + seg * 8);
        *reinterpret_cast<uint4*>(&Bs[r][seg * 8]) = v;
    }
    __syncthreads();

    int wave = tid >> 6, lane = tid & 63;
    int wr = (wave & 1) * 64;
    int wc = (wave >> 1) * 32;
    int lm = lane & 15, lk = (lane >> 4) * 8;
    f32x4 acc[4][2] = {};
#pragma unroll
    for (int kk = 0; kk < 4; ++kk) {
        int k = kk * 32 + lk;
        bf16x8 a[4], bvec[2];
#pragma unroll
        for (int m = 0; m < 4; ++m)
            a[m] = *reinterpret_cast<const bf16x8*>(&As[wr + m * 16 + lm][k]);
#pragma unroll
        for (int n = 0; n < 2; ++n)
            bvec[n] = *reinterpret_cast<const bf16x8*>(&Bs[wc + n * 16 + lm][k]);
#pragma unroll
        for (int m = 0; m < 4; ++m)
#pragma unroll
            for (int n = 0; n < 2; ++n)
                acc[m][n] = __builtin_amdgcn_mfma_f32_16x16x32_bf16(a[m], bvec[n], acc[m][n], 0, 0, 0);
    }
    int r4 = (lane >> 4) * 4;
#pragma unroll
    for (int m = 0; m < 4; ++m) {
#pragma unroll
        for (int r = 0; r < 4; ++r) {
            int grow = row0 + wr + m * 16 + r4 + r;
            if (grow < M) {
#pragma unroll
                for (int n = 0; n < 2; ++n)
                    Hout[(size_t)grow * 640 + col0 + wc + n * 16 + lm] = f2bf(acc[m][n][r]);
            }
        }
    }
}

// ---------------- K4: single-block scan -> rowptr ----------------
__global__ __launch_bounds__(1024) void scan_kernel(const int* __restrict__ deg,
                                                    int* __restrict__ rowptr, int n) {
    __shared__ int lds[1024];
    int t = threadIdx.x;
    const int CH = (n + 1023) / 1024;
    int begin = t * CH;
    int end = begin + CH; if (end > n) end = n;
    int sum = 0;
    for (int i = begin; i < end && i < n; ++i) sum += deg[i];
    lds[t] = sum;
    __syncthreads();
    for (int off = 1; off < 1024; off <<= 1) {
        int v = 0;
        if (t >= off) v = lds[t - off];
        __syncthreads();
        if (t >= off) lds[t] += v;
        __syncthreads();
    }
    int base = (t == 0) ? 0 : lds[t - 1];
    for (int i = begin; i < end && i < n; ++i) {
        rowptr[i] = base;
        base += deg[i];
    }
    if (t == 1023) rowptr[n] = lds[1023];
}

// ---------------- K6: fused softmax + aggregation + epilogue; 1 wave = 1 node ----------------
// lane = 16*g + m : owns head g (g<4) channels m*8..m*8+7 ; head 4 replicated per group.
// 4-edge batched: issue 8 gathers up front, exp overlaps latency, then consume.
__global__ __launch_bounds__(64) void gat_aggregate(
    const int* __restrict__ rowptr, const int* __restrict__ col,
    const float* __restrict__ asrc, const float* __restrict__ adst,
    const ushort* __restrict__ hbf,
    const float* __restrict__ features, const float* __restrict__ bias,
    float* __restrict__ out, int N) {
    int node = blockIdx.x;
    int lane = threadIdx.x;
    int g = lane >> 4, m = lane & 15;
    float adg = adst[node * 5 + g];
    float ad4 = adst[node * 5 + 4];
    int p0 = rowptr[node], p1 = rowptr[node + 1];
    float accG[8] = {}, acc4[8] = {};
    float sg = 0.f, s4 = 0.f;
    int p = p0;
    int nb = (p1 - p0) >> 2;
    for (int it = 0; it < nb; ++it, p += 4) {
        int jj[4];
#pragma unroll
        for (int b = 0; b < 4; ++b) jj[b] = col[p + b];
        uint4 q[4], q4[4];
#pragma unroll
        for (int b = 0; b < 4; ++b) {
            const ushort* hp = hbf + (size_t)jj[b] * 640;
            q[b]  = *reinterpret_cast<const uint4*>(hp + g * 128 + m * 8);
            q4[b] = *reinterpret_cast<const uint4*>(hp + 512 + m * 8);
        }
        float wg[4], w4[4];
#pragma unroll
        for (int b = 0; b < 4; ++b) {
            float eg = asrc[jj[b] * 5 + g] + adg;
            float e4 = asrc[jj[b] * 5 + 4] + ad4;
            eg = (eg > 0.f) ? eg : 0.2f * eg;
            e4 = (e4 > 0.f) ? e4 : 0.2f * e4;
            wg[b] = __expf(eg); w4[b] = __expf(e4);
            sg += wg[b]; s4 += w4[b];
        }
#pragma unroll
        for (int b = 0; b < 4; ++b) {
            uint32_t uu[4] = {q[b].x, q[b].y, q[b].z, q[b].w};
            uint32_t u4[4] = {q4[b].x, q4[b].y, q4[b].z, q4[b].w};
#pragma unroll
            for (int i = 0; i < 4; ++i) {
                float x0 = __uint_as_float(uu[i] << 16);
                float x1 = __uint_as_float(uu[i] & 0xffff0000u);
                accG[2 * i]     = fmaf(wg[b], x0, accG[2 * i]);
                accG[2 * i + 1] = fmaf(wg[b], x1, accG[2 * i + 1]);
                float y0 = __uint_as_float(u4[i] << 16);
                float y1 = __uint_as_float(u4[i] & 0xffff0000u);
                acc4[2 * i]     = fmaf(w4[b], y0, acc4[2 * i]);
                acc4[2 * i + 1] = fmaf(w4[b], y1, acc4[2 * i + 1]);
            }
        }
    }
    for (; p < p1; ++p) {
        int j = col[p];
        float eg = asrc[j * 5 + g] + adg;
        float e4 = asrc[j * 5 + 4] + ad4;
        eg = (eg > 0.f) ? eg : 0.2f * eg;
        e4 = (e4 > 0.f) ? e4 : 0.2f * e4;
        float wg = __expf(eg), w4 = __expf(e4);
        sg += wg; s4 += w4;
        const ushort* hp = hbf + (size_t)j * 640;
        uint4 q  = *reinterpret_cast<const uint4*>(hp + g * 128 + m * 8);
        uint4 q4 = *reinterpret_cast<const uint4*>(hp + 512 + m * 8);
        uint32_t uu[4] = {q.x, q.y, q.z, q.w};
        uint32_t u4[4] = {q4.x, q4.y, q4.z, q4.w};
#pragma unroll
        for (int i = 0; i < 4; ++i) {
            float x0 = __uint_as_float(uu[i] << 16);
            float x1 = __uint_as_float(uu[i] & 0xffff0000u);
            accG[2 * i]     = fmaf(wg, x0, accG[2 * i]);
            accG[2 * i + 1] = fmaf(wg, x1, accG[2 * i + 1]);
            float y0 = __uint_as_float(u4[i] << 16);
            float y1 = __uint_as_float(u4[i] & 0xffff0000u);
            acc4[2 * i]     = fmaf(w4, y0, acc4[2 * i]);
            acc4[2 * i + 1] = fmaf(w4, y1, acc4[2 * i + 1]);
        }
    }
    float invg = 1.f / (sg + 1e-16f);
    float inv4 = 0.25f / (s4 + 1e-16f);
    float r[8];
#pragma unroll
    for (int e = 0; e < 8; ++e) r[e] = accG[e] * invg + acc4[e] * inv4;
#pragma unroll
    for (int e = 0; e < 8; ++e) r[e] += __shfl_xor(r[e], 16, 64);
#pragma unroll
    for (int e = 0; e < 8; ++e) r[e] += __shfl_xor(r[e], 32, 64);
    if (g == 0) {
        int c0 = m * 8;
        size_t base = (size_t)node * 128 + c0;
        float4 f0 = *reinterpret_cast<const float4*>(features + base);
        float4 f1 = *reinterpret_cast<const float4*>(features + base + 4);
        float4 b0 = *reinterpret_cast<const float4*>(bias + c0);
        float4 b1 = *reinterpret_cast<const float4*>(bias + c0 + 4);
        float4 o0, o1;
        o0.x = f0.x + b0.x + 0.2f * r[0];
        o0.y = f0.y + b0.y + 0.2f * r[1];
        o0.z = f0.z + b0.z + 0.2f * r[2];
        o0.w = f0.w + b0.w + 0.2f * r[3];
        o1.x = f1.x + b1.x + 0.2f * r[4];
        o1.y = f1.y + b1.y + 0.2f * r[5];
        o1.z = f1.z + b1.z + 0.2f * r[6];
        o1.w = f1.w + b1.w + 0.2f * r[7];
        *reinterpret_cast<float4*>(out + base) = o0;
        *reinterpret_cast<float4*>(out + base + 4) = o1;
    }
}

// ---------------- launch ----------------
static inline char* bump(char*& p, size_t bytes) {
    char* r = p;
    p += (bytes + 255) & ~(size_t)255;
    return r;
}

extern "C" void kernel_launch(void* const* d_in, const int* in_sizes, int n_in,
                              void* d_out, int out_size, void* d_ws, size_t ws_size,
                              hipStream_t stream) {
    const float* features = (const float*)d_in[0];
    const float* W        = (const float*)d_in[1];
    const float* att_src  = (const float*)d_in[2];
    const float* att_dst  = (const float*)d_in[3];
    const float* bias     = (const float*)d_in[4];
    const int*   edges    = (const int*)d_in[5];

    const int N = in_sizes[0] / C_DIM;
    const int E = in_sizes[5] / 2;
    const int EN = E + N;
    const int* srcArr = edges;
    const int* dstArr = edges + E;

    char* p = (char*)d_ws;
    float* Wa     = (float*)bump(p, C_DIM * 10 * sizeof(float));
    float* asrc   = (float*)bump(p, (size_t)N * 5 * sizeof(float));
    float* adst   = (float*)bump(p, (size_t)N * 5 * sizeof(float));
    ushort* hbf   = (ushort*)bump(p, (size_t)N * 640 * sizeof(ushort));
    ushort* Abf   = (ushort*)bump(p, (size_t)N * C_DIM * sizeof(ushort));
    ushort* Bt    = (ushort*)bump(p, 640 * 128 * sizeof(ushort));
    int* deg      = (int*)bump(p, (size_t)2 * N * sizeof(int));  // deg + cnt adjacent
    int* cnt      = deg + N;
    int* rowptr   = (int*)bump(p, (size_t)(N + 1) * sizeof(int));
    int* col      = (int*)bump(p, (size_t)EN * sizeof(int));

    float* out = (float*)d_out;

    hipMemsetAsync(deg, 0, (size_t)2 * N * sizeof(int), stream);

    // P0: conv_A | conv_Bt | wa | count
    const int B1 = (N * 16 + 255) / 256;
    const int B2 = B1 + (640 * 128 + 255) / 256;
    const int B3 = B2 + (C_DIM * 10 + 255) / 256;
    const int G0 = B3 + (EN + 255) / 256;
    prep0_kernel<<<G0, 256, 0, stream>>>(features, W, att_src, att_dst, Abf, Bt, Wa,
                                         dstArr, deg, B1, B2, B3, N, E);
    // scan
    scan_kernel<<<1, 1024, 0, stream>>>(deg, rowptr, N);
    // P1: alpha | scatter
    const int A1 = (N * 10 + 255) / 256;
    const int G1 = A1 + (EN + 255) / 256;
    prep1_kernel<<<G1, 256, 0, stream>>>(features, Wa, asrc, adst, srcArr, dstArr,
                                         rowptr, cnt, col, A1, N, E);
    // GEMM h
    dim3 ggrid((N + 127) / 128, 10);
    gemm_h_mfma<<<ggrid, 256, 0, stream>>>(Abf, Bt, hbf, N);
    // aggregate + epilogue
    gat_aggregate<<<N, 64, 0, stream>>>(rowptr, col, asrc, adst, hbf, features, bias, out, N);
}